// Round 2
// baseline (63141.992 us; speedup 1.0000x reference)
//
#include <hip/hip_runtime.h>
#include <math.h>

// Problem constants
#define BB 32      // batch
#define SS 64      // sequence length == decode steps
#define HH 256     // hidden
#define G4 1024    // 4*H gate width
#define NT 1024    // threads per block (main kernel)

// ws layout (floats):
//  [0]        8 packed-transposed gate matrices (each 1024x256 -> 256x1024 packed by 4k): 8*262144
//  [2097152]  W1T (k-major 256x256)
//  [2162688]  W2T (k-major 256x256)
//  [2228224]  per-batch scratch, PB floats each:
//             X1[64*1024], preE[64*256], h1c,c1c,h2c,c2c,eW1 (each 64*256)
#define W1T_OFF 2097152
#define W2T_OFF 2162688
#define BATCH_OFF 2228224
#define PB 163840

__device__ __forceinline__ float sigmf(float x) { return 1.0f / (1.0f + expf(-x)); }

// Packed-transpose: dst[((k>>2)*1024 + g)*4 + (k&3)] = src[g*256 + k]
// src: (1024, 256) row-major. Lets the GEMV load 4 consecutive-k weights per float4.
__global__ void pack_transpose_k(const float* __restrict__ s0, const float* __restrict__ s1,
                                 const float* __restrict__ s2, const float* __restrict__ s3,
                                 const float* __restrict__ s4, const float* __restrict__ s5,
                                 const float* __restrict__ s6, const float* __restrict__ s7,
                                 float* __restrict__ ws) {
    __shared__ float tile[64][65];
    const float* srcs[8] = {s0, s1, s2, s3, s4, s5, s6, s7};
    const float* src = srcs[blockIdx.z];
    float* dst = ws + (size_t)blockIdx.z * (G4 * HH);
    int gblk = blockIdx.x * 64;
    int kblk = blockIdx.y * 64;
    for (int q = threadIdx.x; q < 64 * 64; q += 256) {
        int r = q >> 6, c = q & 63;
        tile[r][c] = src[(size_t)(gblk + r) * HH + (kblk + c)];
    }
    __syncthreads();
    for (int q = threadIdx.x; q < 64 * 64; q += 256) {
        int r = q & 3;
        int gl = (q >> 2) & 63;
        int k0l = q >> 8;  // 0..15
        int dsti = (((kblk >> 2) + k0l) * G4 + gblk + gl) * 4 + r;
        dst[dsti] = tile[gl][k0l * 4 + r];
    }
}

// Plain transpose for W1, W2 (256x256): dst[k*256+j] = src[j*256+k]
__global__ void transpose256_k(const float* __restrict__ W1, const float* __restrict__ W2,
                               float* __restrict__ ws) {
    __shared__ float tile[32][33];
    const float* src = blockIdx.z ? W2 : W1;
    float* dst = ws + (blockIdx.z ? W2T_OFF : W1T_OFF);
    int j0 = blockIdx.x * 32, k0 = blockIdx.y * 32;
    int tx = threadIdx.x & 31, ty = threadIdx.x >> 5;
    for (int i = ty; i < 32; i += 8) tile[i][tx] = src[(size_t)(j0 + i) * HH + k0 + tx];
    __syncthreads();
    for (int i = ty; i < 32; i += 8) dst[(size_t)(k0 + i) * HH + j0 + tx] = tile[tx][i];
}

// dot of packed weight column g with LDS vector hs_ (256 long)
__device__ __forceinline__ float dotp(const float4* __restrict__ W4, const float* __restrict__ hs_, int g) {
    float acc = 0.f;
#pragma unroll 4
    for (int k0 = 0; k0 < 64; ++k0) {
        float4 w = W4[(k0 << 10) + g];
        float4 h = *(const float4*)(hs_ + (k0 << 2));
        acc = fmaf(h.x, w.x, acc);
        acc = fmaf(h.y, w.y, acc);
        acc = fmaf(h.z, w.z, acc);
        acc = fmaf(h.w, w.w, acc);
    }
    return acc;
}

__global__ void __launch_bounds__(NT) ptrnet_k(
    const float* __restrict__ inputs, const float* __restrict__ W_emb, const float* __restrict__ b_emb,
    const float* __restrict__ b_e0, const float* __restrict__ b_e1,
    const float* __restrict__ b_d0, const float* __restrict__ b_d1,
    const float* __restrict__ v,
    float* __restrict__ ws, float* __restrict__ out) {
    const int b = blockIdx.x;
    const int tid = threadIdx.x;

    const float4* W4_e0ih = (const float4*)(ws + 0 * 262144);
    const float4* W4_e0hh = (const float4*)(ws + 1 * 262144);
    const float4* W4_e1ih = (const float4*)(ws + 2 * 262144);
    const float4* W4_e1hh = (const float4*)(ws + 3 * 262144);
    const float4* W4_d0ih = (const float4*)(ws + 4 * 262144);
    const float4* W4_d0hh = (const float4*)(ws + 5 * 262144);
    const float4* W4_d1ih = (const float4*)(ws + 6 * 262144);
    const float4* W4_d1hh = (const float4*)(ws + 7 * 262144);
    const float* W1T = ws + W1T_OFF;
    const float* W2T = ws + W2T_OFF;

    float* bws  = ws + BATCH_OFF + (size_t)b * PB;
    float* X1   = bws;             // [64][1024]
    float* preE = X1 + SS * G4;    // [64][256] pre-tanh embeddings
    float* h1c  = preE + SS * HH;  // per-timestep state caches
    float* c1c  = h1c + SS * HH;
    float* h2c  = c1c + SS * HH;   // h2c == enc_out
    float* c2c  = h2c + SS * HH;
    float* eW1  = c2c + SS * HH;   // enc_out @ W1^T cache [64][256]

    __shared__ __align__(16) float g1s[G4];
    __shared__ __align__(16) float h1s[HH], c1s[HH], h2s[HH], c2s[HH];
    __shared__ __align__(16) float dh1s[HH], dc1s[HH], dh2s[HH], dc2s[HH];
    __shared__ __align__(16) float dins[HH], tmps[HH];
    __shared__ float scr[SS];
    __shared__ int msk[SS];
    __shared__ int sel_s;

    // ---- init: preE[t][j] = b_emb[j] + inputs[b,t,:] . W_emb[j,:]
    for (int i = tid; i < SS * HH; i += NT) {
        int t = i >> 8, j = i & 255;
        const float* xr = inputs + ((size_t)b * SS + t) * 8;
        float acc = b_emb[j];
#pragma unroll
        for (int d = 0; d < 8; ++d) acc = fmaf(xr[d], W_emb[j * 8 + d], acc);
        preE[i] = acc;
    }
    if (tid < HH) { h1s[tid] = 0.f; c1s[tid] = 0.f; h2s[tid] = 0.f; c2s[tid] = 0.f; }
    if (tid < SS) msk[tid] = 0;
    __syncthreads();

    // ---- X1[t][g] = b_e0[g] + tanh(preE[t]) . Wih_e0[g,:]
    for (int t = 0; t < SS; ++t) {
        if (tid < HH) tmps[tid] = tanhf(preE[t * HH + tid]);
        __syncthreads();
        X1[t * G4 + tid] = b_e0[tid] + dotp(W4_e0ih, tmps, tid);
        __syncthreads();
    }

    // ---- encoder pass from timestep t0 (states h1s..c2s preset by caller)
    auto encode_from = [&](int t0) {
        for (int t = t0; t < SS; ++t) {
            // layer 1: g = X1[t] + h1 @ Whh0^T
            g1s[tid] = X1[t * G4 + tid] + dotp(W4_e0hh, h1s, tid);
            __syncthreads();
            if (tid < HH) {
                float i_ = sigmf(g1s[tid]);
                float f_ = sigmf(g1s[tid + 256]);
                float gg = tanhf(g1s[tid + 512]);
                float o_ = sigmf(g1s[tid + 768]);
                float c = f_ * c1s[tid] + i_ * gg;
                float h = o_ * tanhf(c);
                c1s[tid] = c; h1s[tid] = h;
                h1c[t * HH + tid] = h; c1c[t * HH + tid] = c;
            }
            __syncthreads();
            // layer 2: g = b1 + h1 @ Wih1^T + h2 @ Whh1^T
            g1s[tid] = b_e1[tid] + dotp(W4_e1ih, h1s, tid) + dotp(W4_e1hh, h2s, tid);
            __syncthreads();
            if (tid < HH) {
                float i_ = sigmf(g1s[tid]);
                float f_ = sigmf(g1s[tid + 256]);
                float gg = tanhf(g1s[tid + 512]);
                float o_ = sigmf(g1s[tid + 768]);
                float c = f_ * c2s[tid] + i_ * gg;
                float h = o_ * tanhf(c);
                c2s[tid] = c; h2s[tid] = h;
                h2c[t * HH + tid] = h; c2c[t * HH + tid] = c;
            }
            __syncthreads();
        }
        // eW1[t][j] = enc_out[t] . W1[j,:]   for t >= t0
        for (int i = tid; i < (SS - t0) * HH; i += NT) {
            int t = t0 + (i >> 8), j = i & 255;
            const float* hr = h2c + t * HH;
            float acc = 0.f;
#pragma unroll 4
            for (int k = 0; k < HH; ++k) acc = fmaf(hr[k], W1T[k * HH + j], acc);
            eW1[t * HH + j] = acc;
        }
        __syncthreads();
    };

    encode_from(0);  // initial full encode (== enc0)

    // ---- decoder init: h,c = final encoder states; dec_in = enc0[:,0]
    if (tid < HH) {
        dh1s[tid] = h1s[tid]; dc1s[tid] = c1s[tid];
        dh2s[tid] = h2s[tid]; dc2s[tid] = c2s[tid];
        dins[tid] = h2c[0 * HH + tid];
    }
    __syncthreads();

    int t0next = 0;
    for (int s = 0; s < SS; ++s) {
        if (s > 0) {
            // reload cached states just before the restart point, then re-encode
            if (tid < HH) {
                if (t0next == 0) {
                    h1s[tid] = 0.f; c1s[tid] = 0.f; h2s[tid] = 0.f; c2s[tid] = 0.f;
                } else {
                    h1s[tid] = h1c[(t0next - 1) * HH + tid];
                    c1s[tid] = c1c[(t0next - 1) * HH + tid];
                    h2s[tid] = h2c[(t0next - 1) * HH + tid];
                    c2s[tid] = c2c[(t0next - 1) * HH + tid];
                }
            }
            __syncthreads();
            encode_from(t0next);
        }

        // ---- decoder cell (2 layers)
        g1s[tid] = b_d0[tid] + dotp(W4_d0ih, dins, tid) + dotp(W4_d0hh, dh1s, tid);
        __syncthreads();
        if (tid < HH) {
            float i_ = sigmf(g1s[tid]);
            float f_ = sigmf(g1s[tid + 256]);
            float gg = tanhf(g1s[tid + 512]);
            float o_ = sigmf(g1s[tid + 768]);
            float c = f_ * dc1s[tid] + i_ * gg;
            float h = o_ * tanhf(c);
            dc1s[tid] = c; dh1s[tid] = h;
        }
        __syncthreads();
        g1s[tid] = b_d1[tid] + dotp(W4_d1ih, dh1s, tid) + dotp(W4_d1hh, dh2s, tid);
        __syncthreads();
        if (tid < HH) {
            float i_ = sigmf(g1s[tid]);
            float f_ = sigmf(g1s[tid + 256]);
            float gg = tanhf(g1s[tid + 512]);
            float o_ = sigmf(g1s[tid + 768]);
            float c = f_ * dc2s[tid] + i_ * gg;
            float h = o_ * tanhf(c);
            dc2s[tid] = c; dh2s[tid] = h;
        }
        __syncthreads();

        // ---- attention: tmps = dec_out @ W2^T
        if (tid < HH) {
            float a2 = 0.f;
#pragma unroll 4
            for (int k = 0; k < HH; ++k) a2 = fmaf(dh2s[k], W2T[k * HH + tid], a2);
            tmps[tid] = a2;
        }
        __syncthreads();
        // scores[t] = v . tanh(eW1[t] + tmps); 16 lanes per t
        {
            int t = tid >> 4, r = tid & 15;
            float a = 0.f;
            for (int j = r; j < HH; j += 16) a += v[j] * tanhf(eW1[t * HH + j] + tmps[j]);
            a += __shfl_xor(a, 8, 16);
            a += __shfl_xor(a, 4, 16);
            a += __shfl_xor(a, 2, 16);
            a += __shfl_xor(a, 1, 16);
            if (r == 0) scr[t] = msk[t] ? -3.0e38f : a;
        }
        __syncthreads();

        // ---- softmax + argmax (first wave, 64 lanes)
        if (tid < SS) {
            float sv = scr[tid];
            float m = sv; int mi = tid;
#pragma unroll
            for (int o = 32; o >= 1; o >>= 1) {
                float ov = __shfl_xor(m, o, 64);
                int oi = __shfl_xor(mi, o, 64);
                if (ov > m || (ov == m && oi < mi)) { m = ov; mi = oi; }
            }
            float e = expf(sv - m);
            float ssum = e;
#pragma unroll
            for (int o = 32; o >= 1; o >>= 1) ssum += __shfl_xor(ssum, o, 64);
            out[((size_t)b * SS + s) * SS + tid] = e / ssum;
            if (tid == 0) {
                sel_s = mi;
                msk[mi] = 1;
                out[(size_t)BB * SS * SS + (size_t)b * SS + s] = (float)mi;
            }
        }
        __syncthreads();

        // ---- bookkeeping for next step
        if (s < SS - 1) {
            int idx = sel_s;
            if (tid < HH) {
                dins[tid] = h2c[idx * HH + tid];  // dec_in = enc_out[idx]
                // cur[b, idx, -1] = 1.0  ->  preE row idx gains W_emb[:, -1]
                tmps[tid] = tanhf(preE[idx * HH + tid] + W_emb[tid * 8 + 7]);
            }
            __syncthreads();
            X1[idx * G4 + tid] = b_e0[tid] + dotp(W4_e0ih, tmps, tid);
            __syncthreads();
            t0next = idx;
        }
    }
}

extern "C" void kernel_launch(void* const* d_in, const int* in_sizes, int n_in,
                              void* d_out, int out_size, void* d_ws, size_t ws_size,
                              hipStream_t stream) {
    const float* inputs = (const float*)d_in[0];
    const float* W_emb  = (const float*)d_in[1];
    const float* b_emb  = (const float*)d_in[2];
    const float* e_Wih0 = (const float*)d_in[3];
    const float* e_Whh0 = (const float*)d_in[4];
    const float* e_b0   = (const float*)d_in[5];
    const float* e_Wih1 = (const float*)d_in[6];
    const float* e_Whh1 = (const float*)d_in[7];
    const float* e_b1   = (const float*)d_in[8];
    const float* d_Wih0 = (const float*)d_in[9];
    const float* d_Whh0 = (const float*)d_in[10];
    const float* d_b0   = (const float*)d_in[11];
    const float* d_Wih1 = (const float*)d_in[12];
    const float* d_Whh1 = (const float*)d_in[13];
    const float* d_b1   = (const float*)d_in[14];
    const float* W1     = (const float*)d_in[15];
    const float* W2     = (const float*)d_in[16];
    const float* v      = (const float*)d_in[17];
    float* ws  = (float*)d_ws;
    float* out = (float*)d_out;

    pack_transpose_k<<<dim3(16, 4, 8), dim3(256), 0, stream>>>(
        e_Wih0, e_Whh0, e_Wih1, e_Whh1, d_Wih0, d_Whh0, d_Wih1, d_Whh1, ws);
    transpose256_k<<<dim3(8, 8, 2), dim3(256), 0, stream>>>(W1, W2, ws);
    ptrnet_k<<<dim3(BB), dim3(NT), 0, stream>>>(
        inputs, W_emb, b_emb, e_b0, e_b1, d_b0, d_b1, v, ws, out);
}